// Round 2
// baseline (11758.262 us; speedup 1.0000x reference)
//
#include <hip/hip_runtime.h>
#include <hip/hip_bf16.h>

typedef __hip_bfloat16 bf16;

#define B_ 4
#define S_ 1024
#define DIM_ 2048
#define H_ 32
#define HD_ 64
#define R_ 16
#define BS_ (B_*S_)   // 4096

__device__ __forceinline__ float b2f(bf16 v){ return __bfloat162float(v); }
__device__ __forceinline__ float elu1f(float x){ return x > 0.f ? x + 1.f : __expf(x); }
__device__ __forceinline__ float sigmoidf(float x){ return 1.f/(1.f + __expf(-x)); }

// dtype-adaptive input read: f=1 -> bf16, f=0 -> fp32. Uniform branch; loads
// are not speculated (pointer not provably dereferenceable), so no OOB.
__device__ __forceinline__ float dread(const void* p, size_t i, int f){
    float r;
    if (f) r = __bfloat162float(((const bf16*)p)[i]);
    else   r = ((const float*)p)[i];
    return r;
}
__device__ __forceinline__ void dwrite(void* p, size_t i, float v, int f){
    if (f) ((bf16*)p)[i] = __float2bfloat16(v);
    else   ((float*)p)[i] = v;
}

// ---------------------------------------------------------------------------
// dtype detect: sample x as bf16; true bf16 N(0,1) data is ~100% in
// (1e-3,1e3); fp32 data decoded as bf16 is ~54% (mantissa-garbage halves).
// ---------------------------------------------------------------------------
__global__ void detect_kernel(const void* __restrict__ x, int* __restrict__ flag){
    __shared__ int cnt[256];
    int t = threadIdx.x;
    int c = 0;
    for (int i = t; i < 4096; i += 256){
        float v = __bfloat162float(((const bf16*)x)[i]);
        float a = fabsf(v);
        if (a > 1e-3f && a < 1e3f) c++;
    }
    cnt[t] = c;
    __syncthreads();
    if (t == 0){
        int s = 0;
        for (int i = 0; i < 256; ++i) s += cnt[i];
        *flag = (s > 3686) ? 1 : 0;   // >90% sane => bf16
    }
}

// ---------------------------------------------------------------------------
// T[z][m][r] = sum_k A[m,k] * L1z[r,k]
// AMODE: 0 = dual-dtype d_in, 1 = bf16 workspace
// ---------------------------------------------------------------------------
template<int AMODE>
__global__ void lowrank_kernel(const void* __restrict__ A,
                               const void* __restrict__ L1a,
                               const void* __restrict__ L1b,
                               const void* __restrict__ L1c,
                               const int* __restrict__ flagp,
                               float* __restrict__ T) {
    int f = *flagp;
    __shared__ float red[256];
    int m = blockIdx.x;
    int z = blockIdx.y;
    const void* L1 = (z==0) ? L1a : ((z==1) ? L1b : L1c);
    int t = threadIdx.x;
    int r = t & 15, seg = t >> 4;
    size_t abase = (size_t)m * DIM_;
    size_t lbase = (size_t)r * DIM_;
    int k0 = seg * (DIM_/16);
    float acc = 0.f;
    for (int k = 0; k < DIM_/16; ++k) {
        float av = (AMODE==1) ? b2f(((const bf16*)A)[abase + k0 + k])
                              : dread(A, abase + k0 + k, f);
        acc += av * dread(L1, lbase + k0 + k, f);
    }
    red[t] = acc;
    __syncthreads();
    if (t < 16) {
        float s = 0.f;
        #pragma unroll
        for (int g = 0; g < 16; ++g) s += red[g*16 + t];
        T[((size_t)z * BS_ + m) * R_ + t] = s;
    }
}

// ---------------------------------------------------------------------------
// C[m,n] = sum_k A[m,k]*W[n,k] + sum_r T[m,r]*L2[n,r]
// M=4096, N=2048, K=2048. 64x64 tile, 256 threads, 4x4 per thread.
// AMODE: 0 = dual d_in, 1 = bf16 ws.  CMODE: 0 = dual d_out, 1 = bf16 ws.
// ---------------------------------------------------------------------------
template<int AMODE, int CMODE>
__global__ __launch_bounds__(256)
void gemm_lr_kernel(const void* __restrict__ A, const void* __restrict__ W,
                    const float* __restrict__ T, const void* __restrict__ L2,
                    const int* __restrict__ flagp, void* __restrict__ C) {
    int f = *flagp;
    __shared__ float As[16][64];
    __shared__ float Bs[16][64];
    int tid = threadIdx.x;
    int tx = tid & 15, ty = tid >> 4;
    int rm0 = blockIdx.y * 64;
    int cn0 = blockIdx.x * 64;
    float acc[4][4] = {};
    int lin = tid * 4;
    int a  = lin >> 4;
    int b0 = lin & 15;
    for (int kk = 0; kk < DIM_; kk += 16) {
        size_t aidx = (size_t)(rm0 + a) * DIM_ + kk + b0;
        size_t widx = (size_t)(cn0 + a) * DIM_ + kk + b0;
        #pragma unroll
        for (int e = 0; e < 4; ++e) {
            As[b0 + e][a] = (AMODE==1) ? b2f(((const bf16*)A)[aidx + e])
                                       : dread(A, aidx + e, f);
            Bs[b0 + e][a] = dread(W, widx + e, f);
        }
        __syncthreads();
        #pragma unroll
        for (int k = 0; k < 16; ++k) {
            float av[4], bv[4];
            #pragma unroll
            for (int i = 0; i < 4; ++i) av[i] = As[k][ty*4+i];
            #pragma unroll
            for (int j = 0; j < 4; ++j) bv[j] = Bs[k][tx*4+j];
            #pragma unroll
            for (int i = 0; i < 4; ++i)
                #pragma unroll
                for (int j = 0; j < 4; ++j) acc[i][j] += av[i]*bv[j];
        }
        __syncthreads();
    }
    // low-rank epilogue
    #pragma unroll
    for (int i = 0; i < 4; ++i) {
        int m = rm0 + ty*4 + i;
        float tm[16];
        #pragma unroll
        for (int r = 0; r < 16; ++r) tm[r] = T[(size_t)m*R_ + r];
        #pragma unroll
        for (int j = 0; j < 4; ++j) {
            int n = cn0 + tx*4 + j;
            float s = 0.f;
            #pragma unroll
            for (int r = 0; r < 16; ++r) s += tm[r] * dread(L2, (size_t)n*R_ + r, f);
            acc[i][j] += s;
        }
    }
    #pragma unroll
    for (int i = 0; i < 4; ++i) {
        int m = rm0 + ty*4 + i;
        #pragma unroll
        for (int j = 0; j < 4; ++j) {
            int n = cn0 + tx*4 + j;
            size_t idx = (size_t)m * DIM_ + n;
            if (CMODE==1) ((bf16*)C)[idx] = __float2bfloat16(acc[i][j]);
            else          dwrite(C, idx, acc[i][j], f);
        }
    }
}

// ---------------------------------------------------------------------------
// qsig[b,h,s] = sigmoid( dot(pq[b,h,:], cache_k[b,s,h,:]) / 8 )
// ---------------------------------------------------------------------------
__global__ void qscore_kernel(const void* __restrict__ pq, const void* __restrict__ ck,
                              const int* __restrict__ flagp, float* __restrict__ qsig) {
    int f = *flagp;
    int tid = threadIdx.x;
    int lane = tid & 63;
    int wid = (blockIdx.x << 2) | (tid >> 6);
    int s = wid & (S_-1);
    int h = (wid >> 10) & (H_-1);
    int b = wid >> 15;
    float p = dread(pq, ((size_t)b*H_ + h)*HD_ + lane, f);
    float k = dread(ck, (((size_t)b*S_ + s)*H_ + h)*HD_ + lane, f);
    float v = p * k;
    for (int off = 32; off; off >>= 1) v += __shfl_xor(v, off, 64);
    if (lane == 0) qsig[((size_t)b*H_ + h)*S_ + s] = sigmoidf(v * 0.125f);
}

// ---------------------------------------------------------------------------
// per (b,h): mem_l/mem_q outer-product accumulation + nrm
// ---------------------------------------------------------------------------
__global__ __launch_bounds__(256)
void mem_kernel(const void* __restrict__ ck, const void* __restrict__ cv,
                const float* __restrict__ qsig,
                const void* __restrict__ meml_in, const void* __restrict__ memq_in,
                const void* __restrict__ norm_in,
                const int* __restrict__ flagp,
                float* __restrict__ meml, float* __restrict__ memq,
                float* __restrict__ nrmt) {
    int f = *flagp;
    __shared__ float ks[4][64], vs[4][64], fv[4][64];
    int bh = blockIdx.x;
    int b = bh >> 5, h = bh & 31;
    int t = threadIdx.x;
    int e = t & 63;
    int dg = t >> 6;
    float accL[16] = {};
    float accQ[16] = {};
    float nsum = 0.f;
    for (int s0 = 0; s0 < S_; s0 += 4) {
        int sl = t >> 6, d = t & 63;
        int s = s0 + sl;
        size_t base = (((size_t)b*S_ + s)*H_ + h)*HD_ + d;
        float kv = elu1f(dread(ck, base, f));
        float vv = dread(cv, base, f);
        float sg = qsig[((size_t)b*H_ + h)*S_ + s];
        ks[sl][d] = kv;
        vs[sl][d] = vv;
        fv[sl][d] = vv * sg;
        __syncthreads();
        #pragma unroll
        for (int s2 = 0; s2 < 4; ++s2) {
            float ve = vs[s2][e];
            float fe = fv[s2][e];
            #pragma unroll
            for (int dd = 0; dd < 16; ++dd) {
                float kk = ks[s2][dg*16 + dd];
                accL[dd] += kk * ve;
                accQ[dd] += kk * fe;
            }
        }
        if (t < 64) {
            #pragma unroll
            for (int s2 = 0; s2 < 4; ++s2) nsum += ks[s2][t];
        }
        __syncthreads();
    }
    size_t mb = (size_t)bh * HD_ * HD_;
    #pragma unroll
    for (int dd = 0; dd < 16; ++dd) {
        int d = dg*16 + dd;
        meml[mb + d*64 + e] = dread(meml_in, mb + d*64 + e, f) + accL[dd];
        memq[mb + d*64 + e] = dread(memq_in, mb + d*64 + e, f) + accQ[dd];
    }
    if (t < 64) nrmt[(size_t)bh*64 + t] = dread(norm_in, (size_t)bh*64 + t, f) + nsum;
}

// ---------------------------------------------------------------------------
// memory readout + per-row gate -> memcomb (bf16, parked in d_out)
// ---------------------------------------------------------------------------
__global__ __launch_bounds__(256)
void memout_kernel(const bf16* __restrict__ xq, const float* __restrict__ meml,
                   const float* __restrict__ memq, const float* __restrict__ nrmt,
                   const void* __restrict__ gw, const void* __restrict__ gb,
                   const int* __restrict__ flagp, bf16* __restrict__ memcomb) {
    int f = *flagp;
    __shared__ float Ml[64][64];
    __shared__ float Mq[64][64];
    __shared__ float nr[64];
    __shared__ float gwv[64];
    __shared__ float sq[4][64];
    int bh = blockIdx.x;
    int b = bh >> 5, h = bh & 31;
    int t = threadIdx.x;
    int w = t >> 6, lane = t & 63;
    size_t mb = (size_t)bh * 4096;
    for (int i = t; i < 4096; i += 256) {
        Ml[i>>6][i&63] = meml[mb + i];
        Mq[i>>6][i&63] = memq[mb + i];
    }
    if (t < 64) { nr[t] = nrmt[(size_t)bh*64 + t]; gwv[t] = dread(gw, t, f); }
    float gbv = dread(gb, 0, f);
    __syncthreads();
    for (int s0 = 0; s0 < S_; s0 += 4) {
        int s = s0 + w;
        float x = b2f(xq[((size_t)(b*S_ + s))*DIM_ + h*64 + lane]);
        float sqv = elu1f(x);
        sq[w][lane] = sqv;
        float dv = sqv * nr[lane];
        for (int off = 32; off; off >>= 1) dv += __shfl_xor(dv, off, 64);
        __syncthreads();
        float mo = 0.f, qmo = 0.f;
        #pragma unroll
        for (int d = 0; d < 64; ++d) {
            float sqd = sq[w][d];
            mo  += sqd * Ml[d][lane];
            qmo += sqd * Mq[d][lane];
        }
        float inv = 1.f / dv;
        mo *= inv; qmo *= inv;
        float gqv = qmo * gwv[lane];
        for (int off = 32; off; off >>= 1) gqv += __shfl_xor(gqv, off, 64);
        float gq = sigmoidf(gqv + gbv);
        memcomb[(((size_t)bh)*S_ + s)*64 + lane] = __float2bfloat16(mo + gq * qmo);
        __syncthreads();
    }
}

// ---------------------------------------------------------------------------
// in-place RoPE on bf16 workspace (B,S,DIM)
// ---------------------------------------------------------------------------
__global__ void rope_kernel(bf16* __restrict__ buf, const void* __restrict__ fcos,
                            const void* __restrict__ fsin,
                            const int* __restrict__ flagp) {
    int f = *flagp;
    int pid = blockIdx.x * 256 + threadIdx.x;
    int cp = pid & 1023;
    int m  = pid >> 10;
    int s  = m & (S_-1);
    int p  = cp & 31;
    float c  = dread(fcos, s*32 + p, f);
    float sn = dread(fsin, s*32 + p, f);
    size_t idx = (size_t)m * DIM_ + cp*2;
    float a = b2f(buf[idx]), b = b2f(buf[idx+1]);
    buf[idx]   = __float2bfloat16(a*c - b*sn);
    buf[idx+1] = __float2bfloat16(a*sn + b*c);
}

// ---------------------------------------------------------------------------
// flash-style causal attention + gate-combine epilogue
// ---------------------------------------------------------------------------
__global__ __launch_bounds__(512)
void attn_kernel(const bf16* __restrict__ qr, const bf16* __restrict__ kr,
                 const bf16* __restrict__ v, const bf16* __restrict__ memcomb,
                 const void* __restrict__ gate, const int* __restrict__ flagp,
                 bf16* __restrict__ outc) {
    int f = *flagp;
    __shared__ float Ks[64][65];
    __shared__ float Vs[64][65];
    __shared__ float qs[16][64];
    __shared__ float ps[16][64];
    int bid = blockIdx.x;
    int qt = bid & 63;
    int h = (bid >> 6) & 31;
    int b = bid >> 11;
    int q0 = qt << 4;
    int t = threadIdx.x;
    int w = t >> 6, lane = t & 63;

    for (int i = t; i < 1024; i += 512) {
        int row = i >> 6, d = i & 63;
        qs[row][d] = b2f(qr[((size_t)(b*S_ + q0 + row))*DIM_ + h*64 + d]);
    }
    float m0 = -1e30f, m1 = -1e30f, l0 = 0.f, l1 = 0.f, O0 = 0.f, O1 = 0.f;
    int r0 = q0 + 2*w, r1 = r0 + 1;
    int nch = ((q0 + 15) >> 6) + 1;
    __syncthreads();

    for (int ch = 0; ch < nch; ++ch) {
        int j0 = ch << 6;
        for (int i = t; i < 4096; i += 512) {
            int row = i >> 6, d = i & 63;
            size_t src = ((size_t)(b*S_ + j0 + row))*DIM_ + h*64 + d;
            Ks[row][d] = b2f(kr[src]);
            Vs[row][d] = b2f(v[src]);
        }
        __syncthreads();
        float a0, a1;
        {   // row r0
            int rl = 2*w;
            float sc = 0.f;
            #pragma unroll
            for (int d = 0; d < 64; ++d) sc += qs[rl][d] * Ks[lane][d];
            sc *= 0.125f;
            if (j0 + lane > r0) sc = -1e30f;
            float mx = sc;
            for (int off = 32; off; off >>= 1) mx = fmaxf(mx, __shfl_xor(mx, off, 64));
            float mn = fmaxf(m0, mx);
            a0 = __expf(m0 - mn);
            float p = __expf(sc - mn);
            float pS = p;
            for (int off = 32; off; off >>= 1) pS += __shfl_xor(pS, off, 64);
            l0 = l0 * a0 + pS;
            m0 = mn;
            ps[rl][lane] = p;
        }
        {   // row r1
            int rl = 2*w + 1;
            float sc = 0.f;
            #pragma unroll
            for (int d = 0; d < 64; ++d) sc += qs[rl][d] * Ks[lane][d];
            sc *= 0.125f;
            if (j0 + lane > r1) sc = -1e30f;
            float mx = sc;
            for (int off = 32; off; off >>= 1) mx = fmaxf(mx, __shfl_xor(mx, off, 64));
            float mn = fmaxf(m1, mx);
            a1 = __expf(m1 - mn);
            float p = __expf(sc - mn);
            float pS = p;
            for (int off = 32; off; off >>= 1) pS += __shfl_xor(pS, off, 64);
            l1 = l1 * a1 + pS;
            m1 = mn;
            ps[rl][lane] = p;
        }
        __syncthreads();
        {
            float acc = 0.f;
            #pragma unroll
            for (int jj = 0; jj < 64; ++jj) acc += ps[2*w][jj] * Vs[jj][lane];
            O0 = O0 * a0 + acc;
        }
        {
            float acc = 0.f;
            #pragma unroll
            for (int jj = 0; jj < 64; ++jj) acc += ps[2*w+1][jj] * Vs[jj][lane];
            O1 = O1 * a1 + acc;
        }
        __syncthreads();
    }

    float g = sigmoidf(dread(gate, h, f));
    {
        float attn = O0 / l0;
        float comb = b2f(memcomb[(((size_t)(b*H_ + h))*S_ + r0)*64 + lane]);
        outc[((size_t)(b*S_ + r0))*DIM_ + h*64 + lane] =
            __float2bfloat16(g*comb + (1.f - g)*attn);
    }
    {
        float attn = O1 / l1;
        float comb = b2f(memcomb[(((size_t)(b*H_ + h))*S_ + r1)*64 + lane]);
        outc[((size_t)(b*S_ + r1))*DIM_ + h*64 + lane] =
            __float2bfloat16(g*comb + (1.f - g)*attn);
    }
}

// ---------------------------------------------------------------------------
extern "C" void kernel_launch(void* const* d_in, const int* in_sizes, int n_in,
                              void* d_out, int out_size, void* d_ws, size_t ws_size,
                              hipStream_t stream) {
    const void* x        = d_in[0];
    const void* pq       = d_in[1];
    const void* cache_k  = d_in[2];
    const void* cache_v  = d_in[3];
    const void* mem_long = d_in[4];
    const void* mem_qry  = d_in[5];
    const void* norm_t   = d_in[6];
    const void* fcos     = d_in[7];
    const void* fsin     = d_in[8];
    // d_in[9] = mask (unused; causal applied analytically)
    const void* wq  = d_in[10];
    const void* wk  = d_in[11];
    const void* wv  = d_in[12];
    const void* wo  = d_in[13];
    const void* lq1 = d_in[14];
    const void* lq2 = d_in[15];
    const void* lk1 = d_in[16];
    const void* lk2 = d_in[17];
    const void* lv1 = d_in[18];
    const void* lv2 = d_in[19];
    const void* lo1 = d_in[20];
    const void* lo2 = d_in[21];
    const void* gate = d_in[22];
    const void* gmw  = d_in[23];
    const void* gmb  = d_in[24];

    const size_t NBSD = (size_t)BS_ * DIM_;   // 8388608
    int*  flag = (int*)d_ws;
    bf16* xq   = (bf16*)((char*)d_ws + 16);
    bf16* xk   = xq + NBSD;
    bf16* xv   = xk + NBSD;
    bf16* outc = xv + NBSD;
    float* Tq  = (float*)(outc + NBSD);
    float* Tk  = Tq + (size_t)BS_*R_;
    float* Tv  = Tk + (size_t)BS_*R_;
    float* To  = Tv + (size_t)BS_*R_;
    float* qsig = To + (size_t)BS_*R_;
    float* meml = qsig + (size_t)B_*H_*S_;
    float* memq = meml + (size_t)B_*H_*HD_*HD_;
    float* nrmt = memq + (size_t)B_*H_*HD_*HD_;
    bf16* memcomb = (bf16*)d_out;   // parked here; final GEMM overwrites d_out

    // 0. dtype detect
    detect_kernel<<<1, 256, 0, stream>>>(x, flag);
    // 1. low-rank temps for q,k,v
    lowrank_kernel<0><<<dim3(BS_, 3), 256, 0, stream>>>(x, lq1, lk1, lv1, flag, Tq);
    // 2. projections -> bf16 ws
    gemm_lr_kernel<0,1><<<dim3(32, 64), 256, 0, stream>>>(x, wq, Tq, lq2, flag, xq);
    gemm_lr_kernel<0,1><<<dim3(32, 64), 256, 0, stream>>>(x, wk, Tk, lk2, flag, xk);
    gemm_lr_kernel<0,1><<<dim3(32, 64), 256, 0, stream>>>(x, wv, Tv, lv2, flag, xv);
    // 3. prompt-query scores
    qscore_kernel<<<(B_*H_*S_)/4, 256, 0, stream>>>(pq, cache_k, flag, qsig);
    // 4. memory accumulation
    mem_kernel<<<B_*H_, 256, 0, stream>>>(cache_k, cache_v, qsig, mem_long, mem_qry,
                                          norm_t, flag, meml, memq, nrmt);
    // 5. memory readout + gate (consumes UN-roped xq)
    memout_kernel<<<B_*H_, 256, 0, stream>>>(xq, meml, memq, nrmt, gmw, gmb, flag, memcomb);
    // 6. RoPE in place
    rope_kernel<<<(BS_*1024)/256, 256, 0, stream>>>(xq, fcos, fsin, flag);
    rope_kernel<<<(BS_*1024)/256, 256, 0, stream>>>(xk, fcos, fsin, flag);
    // 7. causal attention + combine epilogue
    attn_kernel<<<B_*H_*(S_/16), 512, 0, stream>>>(xq, xk, xv, memcomb, gate, flag, outc);
    // 8. output projection (d_out written last, dtype per flag)
    lowrank_kernel<1><<<dim3(BS_, 1), 256, 0, stream>>>(outc, lo1, lo1, lo1, flag, To);
    gemm_lr_kernel<1,0><<<dim3(32, 64), 256, 0, stream>>>(outc, wo, To, lo2, flag, d_out);
}

// Round 3
// 4637.214 us; speedup vs baseline: 2.5356x; 2.5356x over previous
//
#include <hip/hip_runtime.h>
#include <hip/hip_bf16.h>

typedef __hip_bfloat16 bf16;
typedef __attribute__((ext_vector_type(8))) short short8;
typedef __attribute__((ext_vector_type(4))) float floatx4;

#define B_ 4
#define S_ 1024
#define DIM_ 2048
#define H_ 32
#define HD_ 64
#define R_ 16
#define BS_ (B_*S_)   // 4096

typedef __attribute__((address_space(1))) void GVoid;
typedef __attribute__((address_space(3))) void LVoid;
#define GLDS16(gp, lp) __builtin_amdgcn_global_load_lds((GVoid*)(gp), (LVoid*)(lp), 16, 0, 0)

__device__ __forceinline__ float b2f(bf16 v){ return __bfloat162float(v); }
__device__ __forceinline__ float elu1f(float x){ return x > 0.f ? x + 1.f : __expf(x); }
__device__ __forceinline__ float sigmoidf(float x){ return 1.f/(1.f + __expf(-x)); }

// dtype-adaptive input read: f=1 -> bf16, f=0 -> fp32 (uniform branch).
__device__ __forceinline__ float dread(const void* p, size_t i, int f){
    float r;
    if (f) r = __bfloat162float(((const bf16*)p)[i]);
    else   r = ((const float*)p)[i];
    return r;
}
__device__ __forceinline__ void dwrite(void* p, size_t i, float v, int f){
    if (f) ((bf16*)p)[i] = __float2bfloat16(v);
    else   ((float*)p)[i] = v;
}

// ---------------------------------------------------------------------------
// dtype detect (same every call; graph-safe)
// ---------------------------------------------------------------------------
__global__ void detect_kernel(const void* __restrict__ x, int* __restrict__ flag){
    __shared__ int cnt[256];
    int t = threadIdx.x;
    int c = 0;
    for (int i = t; i < 4096; i += 256){
        float v = __bfloat162float(((const bf16*)x)[i]);
        float a = fabsf(v);
        if (a > 1e-3f && a < 1e3f) c++;
    }
    cnt[t] = c;
    __syncthreads();
    if (t == 0){
        int s = 0;
        for (int i = 0; i < 256; ++i) s += cnt[i];
        *flag = (s > 3686) ? 1 : 0;
    }
}

// ---------------------------------------------------------------------------
// convert input (fp32 or bf16 per flag) -> bf16 workspace copy
// ---------------------------------------------------------------------------
__global__ void convert_kernel(const void* __restrict__ src, bf16* __restrict__ dst,
                               int n, const int* __restrict__ flagp){
    int f = *flagp;
    int i = blockIdx.x * 256 + threadIdx.x;
    if (i < n) dst[i] = __float2bfloat16(dread(src, i, f));
}

// ---------------------------------------------------------------------------
// T[z][m][r] = sum_k A[m,k] * L1z[r,k]
// ---------------------------------------------------------------------------
template<int AMODE>   // 0: dual-dtype d_in, 1: bf16 ws
__global__ void lowrank_kernel(const void* __restrict__ A,
                               const void* __restrict__ L1a,
                               const void* __restrict__ L1b,
                               const void* __restrict__ L1c,
                               const int* __restrict__ flagp,
                               float* __restrict__ T) {
    int f = *flagp;
    __shared__ float red[256];
    int m = blockIdx.x;
    int z = blockIdx.y;
    const void* L1 = (z==0) ? L1a : ((z==1) ? L1b : L1c);
    int t = threadIdx.x;
    int r = t & 15, seg = t >> 4;
    size_t abase = (size_t)m * DIM_;
    size_t lbase = (size_t)r * DIM_;
    int k0 = seg * (DIM_/16);
    float acc = 0.f;
    for (int k = 0; k < DIM_/16; ++k) {
        float av = (AMODE==1) ? b2f(((const bf16*)A)[abase + k0 + k])
                              : dread(A, abase + k0 + k, f);
        acc += av * dread(L1, lbase + k0 + k, f);
    }
    red[t] = acc;
    __syncthreads();
    if (t < 16) {
        float s = 0.f;
        #pragma unroll
        for (int g = 0; g < 16; ++g) s += red[g*16 + t];
        T[((size_t)z * BS_ + m) * R_ + t] = s;
    }
}

// ---------------------------------------------------------------------------
// MFMA GEMM: C[m,n] = sum_k A[m,k]*Bw[n,k] + sum_r T[m,r]*L2[n,r]
// A: [4096][2048] bf16, Bw: [2048][2048] bf16 (both K-contiguous).
// 128x128 tile, BK=32, 256 threads (4 waves, 2x2 of 64x64).
// m97 structure: global_load_lds(16B) staging, 2-barrier K-loop,
// mfma_f32_16x16x32_bf16, fp32 accumulate.
// ---------------------------------------------------------------------------
template<int CMODE>   // 1: bf16 ws out; 0: dual-dtype d_out
__global__ __launch_bounds__(256)
void gemm_mfma_kernel(const bf16* __restrict__ A, const bf16* __restrict__ Bw,
                      const float* __restrict__ T, const void* __restrict__ L2,
                      const int* __restrict__ flagp, void* __restrict__ C) {
    __shared__ bf16 Als[128*32];
    __shared__ bf16 Bls[128*32];
    int tid = threadIdx.x;
    int w = tid >> 6, lane = tid & 63;
    int wr = w >> 1, wc = w & 1;
    int rm0 = blockIdx.y * 128;
    int cn0 = blockIdx.x * 128;

    // staging addresses: wave w stages 32 rows of each tile (2 x 16-row insts)
    const bf16* gA = A  + (size_t)(rm0 + w*32 + (lane>>2)) * DIM_ + (lane&3)*8;
    const bf16* gB = Bw + (size_t)(cn0 + w*32 + (lane>>2)) * DIM_ + (lane&3)*8;
    bf16* lA0 = Als + (w*32)*32;
    bf16* lA1 = Als + (w*32+16)*32;
    bf16* lB0 = Bls + (w*32)*32;
    bf16* lB1 = Bls + (w*32+16)*32;

    floatx4 acc[4][4];
    #pragma unroll
    for (int i = 0; i < 4; ++i)
        #pragma unroll
        for (int j = 0; j < 4; ++j) acc[i][j] = (floatx4){0.f,0.f,0.f,0.f};

    // fragment LDS offsets (bf16 elements)
    int aoff[4], boff[4];
    #pragma unroll
    for (int i = 0; i < 4; ++i) {
        aoff[i] = (wr*64 + i*16 + (lane&15))*32 + (lane>>4)*8;
        boff[i] = (wc*64 + i*16 + (lane&15))*32 + (lane>>4)*8;
    }

    for (int kk = 0; kk < DIM_; kk += 32) {
        GLDS16(gA + kk,             lA0);
        GLDS16(gA + 16*DIM_ + kk,   lA1);
        GLDS16(gB + kk,             lB0);
        GLDS16(gB + 16*DIM_ + kk,   lB1);
        __syncthreads();
        short8 af[4], bf_[4];
        #pragma unroll
        for (int i = 0; i < 4; ++i) {
            af[i]  = *(const short8*)(Als + aoff[i]);
            bf_[i] = *(const short8*)(Bls + boff[i]);
        }
        #pragma unroll
        for (int i = 0; i < 4; ++i)
            #pragma unroll
            for (int j = 0; j < 4; ++j)
                acc[i][j] = __builtin_amdgcn_mfma_f32_16x16x32_bf16(
                    af[i], bf_[j], acc[i][j], 0, 0, 0);
        __syncthreads();
    }

    // ---- low-rank epilogue: stage T/L2 tiles into (reused) LDS ----
    int f = *flagp;
    float* Tls  = (float*)Als;   // 128x16 fp32 = 8KB
    float* L2ls = (float*)Bls;
    for (int i2 = tid; i2 < 2048; i2 += 256) {
        Tls[i2]  = T[(size_t)rm0*16 + i2];
        L2ls[i2] = dread(L2, (size_t)cn0*16 + i2, f);
    }
    __syncthreads();

    #pragma unroll
    for (int i = 0; i < 4; ++i) {
        #pragma unroll
        for (int reg = 0; reg < 4; ++reg) {
            int m_loc = wr*64 + i*16 + (lane>>4)*4 + reg;
            const float* tm = Tls + m_loc*16;
            #pragma unroll
            for (int j = 0; j < 4; ++j) {
                int n_loc = wc*64 + j*16 + (lane&15);
                const float* l2 = L2ls + n_loc*16;
                float s = 0.f;
                #pragma unroll
                for (int r = 0; r < 16; ++r) s += tm[r] * l2[r];
                float val = acc[i][j][reg] + s;
                size_t idx = (size_t)(rm0 + m_loc) * DIM_ + cn0 + n_loc;
                if (CMODE==1) ((bf16*)C)[idx] = __float2bfloat16(val);
                else          dwrite(C, idx, val, f);
            }
        }
    }
}

// ---------------------------------------------------------------------------
// qsig[b,h,s] = sigmoid( dot(pq[b,h,:], cache_k[b,s,h,:]) / 8 )
// ---------------------------------------------------------------------------
__global__ void qscore_kernel(const void* __restrict__ pq, const void* __restrict__ ck,
                              const int* __restrict__ flagp, float* __restrict__ qsig) {
    int f = *flagp;
    int tid = threadIdx.x;
    int lane = tid & 63;
    int wid = (blockIdx.x << 2) | (tid >> 6);
    int s = wid & (S_-1);
    int h = (wid >> 10) & (H_-1);
    int b = wid >> 15;
    float p = dread(pq, ((size_t)b*H_ + h)*HD_ + lane, f);
    float k = dread(ck, (((size_t)b*S_ + s)*H_ + h)*HD_ + lane, f);
    float v = p * k;
    for (int off = 32; off; off >>= 1) v += __shfl_xor(v, off, 64);
    if (lane == 0) qsig[((size_t)b*H_ + h)*S_ + s] = sigmoidf(v * 0.125f);
}

// ---------------------------------------------------------------------------
// per (b,h): mem_l/mem_q outer-product accumulation + nrm
// ---------------------------------------------------------------------------
__global__ __launch_bounds__(256)
void mem_kernel(const void* __restrict__ ck, const void* __restrict__ cv,
                const float* __restrict__ qsig,
                const void* __restrict__ meml_in, const void* __restrict__ memq_in,
                const void* __restrict__ norm_in,
                const int* __restrict__ flagp,
                float* __restrict__ meml, float* __restrict__ memq,
                float* __restrict__ nrmt) {
    int f = *flagp;
    __shared__ float ks[4][64], vs[4][64], fv[4][64];
    int bh = blockIdx.x;
    int b = bh >> 5, h = bh & 31;
    int t = threadIdx.x;
    int e = t & 63;
    int dg = t >> 6;
    float accL[16] = {};
    float accQ[16] = {};
    float nsum = 0.f;
    for (int s0 = 0; s0 < S_; s0 += 4) {
        int sl = t >> 6, d = t & 63;
        int s = s0 + sl;
        size_t base = (((size_t)b*S_ + s)*H_ + h)*HD_ + d;
        float kv = elu1f(dread(ck, base, f));
        float vv = dread(cv, base, f);
        float sg = qsig[((size_t)b*H_ + h)*S_ + s];
        ks[sl][d] = kv;
        vs[sl][d] = vv;
        fv[sl][d] = vv * sg;
        __syncthreads();
        #pragma unroll
        for (int s2 = 0; s2 < 4; ++s2) {
            float ve = vs[s2][e];
            float fe = fv[s2][e];
            #pragma unroll
            for (int dd = 0; dd < 16; ++dd) {
                float kk = ks[s2][dg*16 + dd];
                accL[dd] += kk * ve;
                accQ[dd] += kk * fe;
            }
        }
        if (t < 64) {
            #pragma unroll
            for (int s2 = 0; s2 < 4; ++s2) nsum += ks[s2][t];
        }
        __syncthreads();
    }
    size_t mb = (size_t)bh * HD_ * HD_;
    #pragma unroll
    for (int dd = 0; dd < 16; ++dd) {
        int d = dg*16 + dd;
        meml[mb + d*64 + e] = dread(meml_in, mb + d*64 + e, f) + accL[dd];
        memq[mb + d*64 + e] = dread(memq_in, mb + d*64 + e, f) + accQ[dd];
    }
    if (t < 64) nrmt[(size_t)bh*64 + t] = dread(norm_in, (size_t)bh*64 + t, f) + nsum;
}

// ---------------------------------------------------------------------------
// memory readout + per-row gate -> memcomb (bf16, parked in d_out)
// ---------------------------------------------------------------------------
__global__ __launch_bounds__(256)
void memout_kernel(const bf16* __restrict__ xq, const float* __restrict__ meml,
                   const float* __restrict__ memq, const float* __restrict__ nrmt,
                   const void* __restrict__ gw, const void* __restrict__ gb,
                   const int* __restrict__ flagp, bf16* __restrict__ memcomb) {
    int f = *flagp;
    __shared__ float Ml[64][64];
    __shared__ float Mq[64][64];
    __shared__ float nr[64];
    __shared__ float gwv[64];
    __shared__ float sq[4][64];
    int bh = blockIdx.x;
    int b = bh >> 5, h = bh & 31;
    int t = threadIdx.x;
    int w = t >> 6, lane = t & 63;
    size_t mb = (size_t)bh * 4096;
    for (int i = t; i < 4096; i += 256) {
        Ml[i>>6][i&63] = meml[mb + i];
        Mq[i>>6][i&63] = memq[mb + i];
    }
    if (t < 64) { nr[t] = nrmt[(size_t)bh*64 + t]; gwv[t] = dread(gw, t, f); }
    float gbv = dread(gb, 0, f);
    __syncthreads();
    for (int s0 = 0; s0 < S_; s0 += 4) {
        int s = s0 + w;
        float x = b2f(xq[((size_t)(b*S_ + s))*DIM_ + h*64 + lane]);
        float sqv = elu1f(x);
        sq[w][lane] = sqv;
        float dv = sqv * nr[lane];
        for (int off = 32; off; off >>= 1) dv += __shfl_xor(dv, off, 64);
        __syncthreads();
        float mo = 0.f, qmo = 0.f;
        #pragma unroll
        for (int d = 0; d < 64; ++d) {
            float sqd = sq[w][d];
            mo  += sqd * Ml[d][lane];
            qmo += sqd * Mq[d][lane];
        }
        float inv = 1.f / dv;
        mo *= inv; qmo *= inv;
        float gqv = qmo * gwv[lane];
        for (int off = 32; off; off >>= 1) gqv += __shfl_xor(gqv, off, 64);
        float gq = sigmoidf(gqv + gbv);
        memcomb[(((size_t)bh)*S_ + s)*64 + lane] = __float2bfloat16(mo + gq * qmo);
        __syncthreads();
    }
}

// ---------------------------------------------------------------------------
// in-place RoPE on bf16 workspace (B,S,DIM)
// ---------------------------------------------------------------------------
__global__ void rope_kernel(bf16* __restrict__ buf, const void* __restrict__ fcos,
                            const void* __restrict__ fsin,
                            const int* __restrict__ flagp) {
    int f = *flagp;
    int pid = blockIdx.x * 256 + threadIdx.x;
    int cp = pid & 1023;
    int m  = pid >> 10;
    int s  = m & (S_-1);
    int p  = cp & 31;
    float c  = dread(fcos, s*32 + p, f);
    float sn = dread(fsin, s*32 + p, f);
    size_t idx = (size_t)m * DIM_ + cp*2;
    float a = b2f(buf[idx]), b = b2f(buf[idx+1]);
    buf[idx]   = __float2bfloat16(a*c - b*sn);
    buf[idx+1] = __float2bfloat16(a*sn + b*c);
}

// ---------------------------------------------------------------------------
// flash-style causal attention + gate-combine epilogue
// ---------------------------------------------------------------------------
__global__ __launch_bounds__(512)
void attn_kernel(const bf16* __restrict__ qr, const bf16* __restrict__ kr,
                 const bf16* __restrict__ v, const bf16* __restrict__ memcomb,
                 const void* __restrict__ gate, const int* __restrict__ flagp,
                 bf16* __restrict__ outc) {
    int f = *flagp;
    __shared__ float Ks[64][65];
    __shared__ float Vs[64][65];
    __shared__ float qs[16][64];
    __shared__ float ps[16][64];
    int bid = blockIdx.x;
    int qt = bid & 63;
    int h = (bid >> 6) & 31;
    int b = bid >> 11;
    int q0 = qt << 4;
    int t = threadIdx.x;
    int w = t >> 6, lane = t & 63;

    for (int i = t; i < 1024; i += 512) {
        int row = i >> 6, d = i & 63;
        qs[row][d] = b2f(qr[((size_t)(b*S_ + q0 + row))*DIM_ + h*64 + d]);
    }
    float m0 = -1e30f, m1 = -1e30f, l0 = 0.f, l1 = 0.f, O0 = 0.f, O1 = 0.f;
    int r0 = q0 + 2*w, r1 = r0 + 1;
    int nch = ((q0 + 15) >> 6) + 1;
    __syncthreads();

    for (int ch = 0; ch < nch; ++ch) {
        int j0 = ch << 6;
        for (int i = t; i < 4096; i += 512) {
            int row = i >> 6, d = i & 63;
            size_t src = ((size_t)(b*S_ + j0 + row))*DIM_ + h*64 + d;
            Ks[row][d] = b2f(kr[src]);
            Vs[row][d] = b2f(v[src]);
        }
        __syncthreads();
        float a0, a1;
        {
            int rl = 2*w;
            float sc = 0.f;
            #pragma unroll
            for (int d = 0; d < 64; ++d) sc += qs[rl][d] * Ks[lane][d];
            sc *= 0.125f;
            if (j0 + lane > r0) sc = -1e30f;
            float mx = sc;
            for (int off = 32; off; off >>= 1) mx = fmaxf(mx, __shfl_xor(mx, off, 64));
            float mn = fmaxf(m0, mx);
            a0 = __expf(m0 - mn);
            float p = __expf(sc - mn);
            float pS = p;
            for (int off = 32; off; off >>= 1) pS += __shfl_xor(pS, off, 64);
            l0 = l0 * a0 + pS;
            m0 = mn;
            ps[rl][lane] = p;
        }
        {
            int rl = 2*w + 1;
            float sc = 0.f;
            #pragma unroll
            for (int d = 0; d < 64; ++d) sc += qs[rl][d] * Ks[lane][d];
            sc *= 0.125f;
            if (j0 + lane > r1) sc = -1e30f;
            float mx = sc;
            for (int off = 32; off; off >>= 1) mx = fmaxf(mx, __shfl_xor(mx, off, 64));
            float mn = fmaxf(m1, mx);
            a1 = __expf(m1 - mn);
            float p = __expf(sc - mn);
            float pS = p;
            for (int off = 32; off; off >>= 1) pS += __shfl_xor(pS, off, 64);
            l1 = l1 * a1 + pS;
            m1 = mn;
            ps[rl][lane] = p;
        }
        __syncthreads();
        {
            float acc = 0.f;
            #pragma unroll
            for (int jj = 0; jj < 64; ++jj) acc += ps[2*w][jj] * Vs[jj][lane];
            O0 = O0 * a0 + acc;
        }
        {
            float acc = 0.f;
            #pragma unroll
            for (int jj = 0; jj < 64; ++jj) acc += ps[2*w+1][jj] * Vs[jj][lane];
            O1 = O1 * a1 + acc;
        }
        __syncthreads();
    }

    float g = sigmoidf(dread(gate, h, f));
    {
        float attn = O0 / l0;
        float comb = b2f(memcomb[(((size_t)(b*H_ + h))*S_ + r0)*64 + lane]);
        outc[((size_t)(b*S_ + r0))*DIM_ + h*64 + lane] =
            __float2bfloat16(g*comb + (1.f - g)*attn);
    }
    {
        float attn = O1 / l1;
        float comb = b2f(memcomb[(((size_t)(b*H_ + h))*S_ + r1)*64 + lane]);
        outc[((size_t)(b*S_ + r1))*DIM_ + h*64 + lane] =
            __float2bfloat16(g*comb + (1.f - g)*attn);
    }
}

// ---------------------------------------------------------------------------
extern "C" void kernel_launch(void* const* d_in, const int* in_sizes, int n_in,
                              void* d_out, int out_size, void* d_ws, size_t ws_size,
                              hipStream_t stream) {
    const void* x        = d_in[0];
    const void* pq       = d_in[1];
    const void* cache_k  = d_in[2];
    const void* cache_v  = d_in[3];
    const void* mem_long = d_in[4];
    const void* mem_qry  = d_in[5];
    const void* norm_t   = d_in[6];
    const void* fcos     = d_in[7];
    const void* fsin     = d_in[8];
    // d_in[9] = mask (unused; causal applied analytically)
    const void* wq  = d_in[10];
    const void* wk  = d_in[11];
    const void* wv  = d_in[12];
    const void* wo  = d_in[13];
    const void* lq1 = d_in[14];
    const void* lq2 = d_in[15];
    const void* lk1 = d_in[16];
    const void* lk2 = d_in[17];
    const void* lv1 = d_in[18];
    const void* lv2 = d_in[19];
    const void* lo1 = d_in[20];
    const void* lo2 = d_in[21];
    const void* gate = d_in[22];
    const void* gmw  = d_in[23];
    const void* gmb  = d_in[24];

    const size_t NBSD = (size_t)BS_ * DIM_;   // 8388608
    const size_t NW   = (size_t)DIM_ * DIM_;  // 4194304
    int*  flag = (int*)d_ws;
    bf16* xb   = (bf16*)((char*)d_ws + 16);   // converted x
    bf16* wbuf = xb + NBSD;                   // converted active weight
    bf16* xq   = wbuf + NW;
    bf16* xk   = xq + NBSD;
    bf16* xv   = xk + NBSD;
    bf16* outc = xv + NBSD;
    float* Tq  = (float*)(outc + NBSD);
    float* Tk  = Tq + (size_t)BS_*R_;
    float* Tv  = Tk + (size_t)BS_*R_;
    float* To  = Tv + (size_t)BS_*R_;
    float* qsig = To + (size_t)BS_*R_;
    float* meml = qsig + (size_t)B_*H_*S_;
    float* memq = meml + (size_t)B_*H_*HD_*HD_;
    float* nrmt = memq + (size_t)B_*H_*HD_*HD_;
    bf16* memcomb = (bf16*)d_out;   // parked; final GEMM overwrites d_out

    dim3 ggrid(DIM_/128, BS_/128);  // (16, 32)

    // 0. dtype detect
    detect_kernel<<<1, 256, 0, stream>>>(x, flag);
    // 1. convert x to bf16
    convert_kernel<<<(int)(NBSD/256), 256, 0, stream>>>(x, xb, (int)NBSD, flag);
    // 2. low-rank temps for q,k,v
    lowrank_kernel<0><<<dim3(BS_, 3), 256, 0, stream>>>(x, lq1, lk1, lv1, flag, Tq);
    // 3. projections (MFMA): convert weight, then GEMM
    convert_kernel<<<(int)(NW/256), 256, 0, stream>>>(wq, wbuf, (int)NW, flag);
    gemm_mfma_kernel<1><<<ggrid, 256, 0, stream>>>(xb, wbuf, Tq, lq2, flag, xq);
    convert_kernel<<<(int)(NW/256), 256, 0, stream>>>(wk, wbuf, (int)NW, flag);
    gemm_mfma_kernel<1><<<ggrid, 256, 0, stream>>>(xb, wbuf, Tk, lk2, flag, xk);
    convert_kernel<<<(int)(NW/256), 256, 0, stream>>>(wv, wbuf, (int)NW, flag);
    gemm_mfma_kernel<1><<<ggrid, 256, 0, stream>>>(xb, wbuf, Tv, lv2, flag, xv);
    // 4. prompt-query scores
    qscore_kernel<<<(B_*H_*S_)/4, 256, 0, stream>>>(pq, cache_k, flag, qsig);
    // 5. memory accumulation
    mem_kernel<<<B_*H_, 256, 0, stream>>>(cache_k, cache_v, qsig, mem_long, mem_qry,
                                          norm_t, flag, meml, memq, nrmt);
    // 6. memory readout + gate (consumes UN-roped xq)
    memout_kernel<<<B_*H_, 256, 0, stream>>>(xq, meml, memq, nrmt, gmw, gmb, flag, memcomb);
    // 7. RoPE in place
    rope_kernel<<<(BS_*1024)/256, 256, 0, stream>>>(xq, fcos, fsin, flag);
    rope_kernel<<<(BS_*1024)/256, 256, 0, stream>>>(xk, fcos, fsin, flag);
    // 8. causal attention + combine epilogue
    attn_kernel<<<B_*H_*(S_/16), 512, 0, stream>>>(xq, xk, xv, memcomb, gate, flag, outc);
    // 9. output projection (MFMA)
    lowrank_kernel<1><<<dim3(BS_, 1), 256, 0, stream>>>(outc, lo1, lo1, lo1, flag, To);
    convert_kernel<<<(int)(NW/256), 256, 0, stream>>>(wo, wbuf, (int)NW, flag);
    gemm_mfma_kernel<0><<<ggrid, 256, 0, stream>>>(outc, wbuf, To, lo2, flag, d_out);
}

// Round 4
// 2566.303 us; speedup vs baseline: 4.5818x; 1.8070x over previous
//
#include <hip/hip_runtime.h>
#include <hip/hip_bf16.h>

typedef __hip_bfloat16 bf16;
typedef __attribute__((ext_vector_type(8))) short short8;
typedef __attribute__((ext_vector_type(4))) float floatx4;

#define B_ 4
#define S_ 1024
#define DIM_ 2048
#define H_ 32
#define HD_ 64
#define R_ 16
#define BS_ (B_*S_)   // 4096

typedef __attribute__((address_space(1))) void GVoid;
typedef __attribute__((address_space(3))) void LVoid;
#define GLDS16(gp, lp) __builtin_amdgcn_global_load_lds((GVoid*)(gp), (LVoid*)(lp), 16, 0, 0)

__device__ __forceinline__ float b2f(bf16 v){ return __bfloat162float(v); }
__device__ __forceinline__ float elu1f(float x){ return x > 0.f ? x + 1.f : __expf(x); }
__device__ __forceinline__ float sigmoidf(float x){ return 1.f/(1.f + __expf(-x)); }
__device__ __forceinline__ float loadf(bf16 v){ return __bfloat162float(v); }
__device__ __forceinline__ float loadf(float v){ return v; }

// dtype-adaptive input read: f=1 -> bf16, f=0 -> fp32 (uniform branch).
__device__ __forceinline__ float dread(const void* p, size_t i, int f){
    float r;
    if (f) r = __bfloat162float(((const bf16*)p)[i]);
    else   r = ((const float*)p)[i];
    return r;
}
__device__ __forceinline__ void dwrite(void* p, size_t i, float v, int f){
    if (f) ((bf16*)p)[i] = __float2bfloat16(v);
    else   ((float*)p)[i] = v;
}

// ---------------------------------------------------------------------------
// dtype detect (same every call; graph-safe)
// ---------------------------------------------------------------------------
__global__ void detect_kernel(const void* __restrict__ x, int* __restrict__ flag){
    __shared__ int cnt[256];
    int t = threadIdx.x;
    int c = 0;
    for (int i = t; i < 4096; i += 256){
        float v = __bfloat162float(((const bf16*)x)[i]);
        float a = fabsf(v);
        if (a > 1e-3f && a < 1e3f) c++;
    }
    cnt[t] = c;
    __syncthreads();
    if (t == 0){
        int s = 0;
        for (int i = 0; i < 256; ++i) s += cnt[i];
        *flag = (s > 3686) ? 1 : 0;
    }
}

// ---------------------------------------------------------------------------
// convert input (fp32 or bf16 per flag) -> bf16 workspace copy
// ---------------------------------------------------------------------------
template<typename T>
__device__ __forceinline__ void convert_body(const T* __restrict__ src,
                                             bf16* __restrict__ dst, int n){
    int i = blockIdx.x * 256 + threadIdx.x;
    if (i < n) dst[i] = __float2bfloat16(loadf(src[i]));
}
__global__ void convert_kernel(const void* __restrict__ src, bf16* __restrict__ dst,
                               int n, const int* __restrict__ flagp){
    if (*flagp) convert_body((const bf16*)src, dst, n);
    else        convert_body((const float*)src, dst, n);
}

// ---------------------------------------------------------------------------
// fused weight prep: W'[n,k] = W[n,k] + sum_r L2[n,r] * L1[r,k]   -> bf16
// grid (DIM_/256, DIM_); folds the rank-16 term into the weight so the
// low-rank pass and GEMM epilogue disappear entirely.
// ---------------------------------------------------------------------------
template<typename T>
__device__ __forceinline__ void wprep_body(const T* __restrict__ W,
                                           const T* __restrict__ L1,
                                           const T* __restrict__ L2,
                                           bf16* __restrict__ dst){
    int n = blockIdx.y;
    int k = blockIdx.x * 256 + threadIdx.x;
    size_t nk = (size_t)n * DIM_ + k;
    float acc = loadf(W[nk]);
    #pragma unroll
    for (int r = 0; r < 16; ++r)
        acc += loadf(L2[n*16 + r]) * loadf(L1[(size_t)r*DIM_ + k]);
    dst[nk] = __float2bfloat16(acc);
}
__global__ __launch_bounds__(256)
void wprep_kernel(const void* __restrict__ W, const void* __restrict__ L1,
                  const void* __restrict__ L2, const int* __restrict__ flagp,
                  bf16* __restrict__ dst){
    if (*flagp) wprep_body((const bf16*)W, (const bf16*)L1, (const bf16*)L2, dst);
    else        wprep_body((const float*)W, (const float*)L1, (const float*)L2, dst);
}

// ---------------------------------------------------------------------------
// MFMA GEMM: C[m,n] = sum_k A[m,k]*Bw[n,k]
// A: [4096][2048] bf16, Bw: [2048][2048] bf16 (both K-contiguous).
// 128x128 tile, BK=32, 256 threads (4 waves, 2x2 of 64x64), m97 structure.
// ---------------------------------------------------------------------------
template<int CMODE>   // 1: bf16 ws out; 0: dual-dtype d_out
__global__ __launch_bounds__(256)
void gemm_mfma_kernel(const bf16* __restrict__ A, const bf16* __restrict__ Bw,
                      const int* __restrict__ flagp, void* __restrict__ C) {
    __shared__ bf16 Als[128*32];
    __shared__ bf16 Bls[128*32];
    int tid = threadIdx.x;
    int w = tid >> 6, lane = tid & 63;
    int wr = w >> 1, wc = w & 1;
    int rm0 = blockIdx.y * 128;
    int cn0 = blockIdx.x * 128;

    const bf16* gA = A  + (size_t)(rm0 + w*32 + (lane>>2)) * DIM_ + (lane&3)*8;
    const bf16* gB = Bw + (size_t)(cn0 + w*32 + (lane>>2)) * DIM_ + (lane&3)*8;
    bf16* lA0 = Als + (w*32)*32;
    bf16* lA1 = Als + (w*32+16)*32;
    bf16* lB0 = Bls + (w*32)*32;
    bf16* lB1 = Bls + (w*32+16)*32;

    floatx4 acc[4][4];
    #pragma unroll
    for (int i = 0; i < 4; ++i)
        #pragma unroll
        for (int j = 0; j < 4; ++j) acc[i][j] = (floatx4){0.f,0.f,0.f,0.f};

    int aoff[4], boff[4];
    #pragma unroll
    for (int i = 0; i < 4; ++i) {
        aoff[i] = (wr*64 + i*16 + (lane&15))*32 + (lane>>4)*8;
        boff[i] = (wc*64 + i*16 + (lane&15))*32 + (lane>>4)*8;
    }

    for (int kk = 0; kk < DIM_; kk += 32) {
        GLDS16(gA + kk,             lA0);
        GLDS16(gA + 16*DIM_ + kk,   lA1);
        GLDS16(gB + kk,             lB0);
        GLDS16(gB + 16*DIM_ + kk,   lB1);
        __syncthreads();
        short8 af[4], bf_[4];
        #pragma unroll
        for (int i = 0; i < 4; ++i) {
            af[i]  = *(const short8*)(Als + aoff[i]);
            bf_[i] = *(const short8*)(Bls + boff[i]);
        }
        #pragma unroll
        for (int i = 0; i < 4; ++i)
            #pragma unroll
            for (int j = 0; j < 4; ++j)
                acc[i][j] = __builtin_amdgcn_mfma_f32_16x16x32_bf16(
                    af[i], bf_[j], acc[i][j], 0, 0, 0);
        __syncthreads();
    }

    int f = (CMODE==0) ? *flagp : 1;
    #pragma unroll
    for (int i = 0; i < 4; ++i) {
        #pragma unroll
        for (int reg = 0; reg < 4; ++reg) {
            int m_loc = wr*64 + i*16 + (lane>>4)*4 + reg;
            #pragma unroll
            for (int j = 0; j < 4; ++j) {
                int n_loc = wc*64 + j*16 + (lane&15);
                float val = acc[i][j][reg];
                size_t idx = (size_t)(rm0 + m_loc) * DIM_ + cn0 + n_loc;
                if (CMODE==1) ((bf16*)C)[idx] = __float2bfloat16(val);
                else          dwrite(C, idx, val, f);
            }
        }
    }
}

// ---------------------------------------------------------------------------
// qsig[b,h,s] = sigmoid( dot(pq[b,h,:], cache_k[b,s,h,:]) / 8 )
// ---------------------------------------------------------------------------
__global__ void qscore_kernel(const void* __restrict__ pq, const void* __restrict__ ck,
                              const int* __restrict__ flagp, float* __restrict__ qsig) {
    int f = *flagp;
    int tid = threadIdx.x;
    int lane = tid & 63;
    int wid = (blockIdx.x << 2) | (tid >> 6);
    int s = wid & (S_-1);
    int h = (wid >> 10) & (H_-1);
    int b = wid >> 15;
    float p = dread(pq, ((size_t)b*H_ + h)*HD_ + lane, f);
    float k = dread(ck, (((size_t)b*S_ + s)*H_ + h)*HD_ + lane, f);
    float v = p * k;
    for (int off = 32; off; off >>= 1) v += __shfl_xor(v, off, 64);
    if (lane == 0) qsig[((size_t)b*H_ + h)*S_ + s] = sigmoidf(v * 0.125f);
}

// ---------------------------------------------------------------------------
// per (b,h): mem_l/mem_q outer-product accumulation + nrm
// ---------------------------------------------------------------------------
__global__ __launch_bounds__(256)
void mem_kernel(const void* __restrict__ ck, const void* __restrict__ cv,
                const float* __restrict__ qsig,
                const void* __restrict__ meml_in, const void* __restrict__ memq_in,
                const void* __restrict__ norm_in,
                const int* __restrict__ flagp,
                float* __restrict__ meml, float* __restrict__ memq,
                float* __restrict__ nrmt) {
    int f = *flagp;
    __shared__ float ks[4][64], vs[4][64], fv[4][64];
    int bh = blockIdx.x;
    int b = bh >> 5, h = bh & 31;
    int t = threadIdx.x;
    int e = t & 63;
    int dg = t >> 6;
    float accL[16] = {};
    float accQ[16] = {};
    float nsum = 0.f;
    for (int s0 = 0; s0 < S_; s0 += 4) {
        int sl = t >> 6, d = t & 63;
        int s = s0 + sl;
        size_t base = (((size_t)b*S_ + s)*H_ + h)*HD_ + d;
        float kv = elu1f(dread(ck, base, f));
        float vv = dread(cv, base, f);
        float sg = qsig[((size_t)b*H_ + h)*S_ + s];
        ks[sl][d] = kv;
        vs[sl][d] = vv;
        fv[sl][d] = vv * sg;
        __syncthreads();
        #pragma unroll
        for (int s2 = 0; s2 < 4; ++s2) {
            float ve = vs[s2][e];
            float fe = fv[s2][e];
            #pragma unroll
            for (int dd = 0; dd < 16; ++dd) {
                float kk = ks[s2][dg*16 + dd];
                accL[dd] += kk * ve;
                accQ[dd] += kk * fe;
            }
        }
        if (t < 64) {
            #pragma unroll
            for (int s2 = 0; s2 < 4; ++s2) nsum += ks[s2][t];
        }
        __syncthreads();
    }
    size_t mb = (size_t)bh * HD_ * HD_;
    #pragma unroll
    for (int dd = 0; dd < 16; ++dd) {
        int d = dg*16 + dd;
        meml[mb + d*64 + e] = dread(meml_in, mb + d*64 + e, f) + accL[dd];
        memq[mb + d*64 + e] = dread(memq_in, mb + d*64 + e, f) + accQ[dd];
    }
    if (t < 64) nrmt[(size_t)bh*64 + t] = dread(norm_in, (size_t)bh*64 + t, f) + nsum;
}

// ---------------------------------------------------------------------------
// memory readout + per-row gate -> memcomb (bf16, parked in d_out)
// ---------------------------------------------------------------------------
__global__ __launch_bounds__(256)
void memout_kernel(const bf16* __restrict__ xq, const float* __restrict__ meml,
                   const float* __restrict__ memq, const float* __restrict__ nrmt,
                   const void* __restrict__ gw, const void* __restrict__ gb,
                   const int* __restrict__ flagp, bf16* __restrict__ memcomb) {
    int f = *flagp;
    __shared__ float Ml[64][64];
    __shared__ float Mq[64][64];
    __shared__ float nr[64];
    __shared__ float gwv[64];
    __shared__ float sq[4][64];
    int bh = blockIdx.x;
    int b = bh >> 5, h = bh & 31;
    int t = threadIdx.x;
    int w = t >> 6, lane = t & 63;
    size_t mb = (size_t)bh * 4096;
    for (int i = t; i < 4096; i += 256) {
        Ml[i>>6][i&63] = meml[mb + i];
        Mq[i>>6][i&63] = memq[mb + i];
    }
    if (t < 64) { nr[t] = nrmt[(size_t)bh*64 + t]; gwv[t] = dread(gw, t, f); }
    float gbv = dread(gb, 0, f);
    __syncthreads();
    for (int s0 = 0; s0 < S_; s0 += 4) {
        int s = s0 + w;
        float x = b2f(xq[((size_t)(b*S_ + s))*DIM_ + h*64 + lane]);
        float sqv = elu1f(x);
        sq[w][lane] = sqv;
        float dv = sqv * nr[lane];
        for (int off = 32; off; off >>= 1) dv += __shfl_xor(dv, off, 64);
        __syncthreads();
        float mo = 0.f, qmo = 0.f;
        #pragma unroll
        for (int d = 0; d < 64; ++d) {
            float sqd = sq[w][d];
            mo  += sqd * Ml[d][lane];
            qmo += sqd * Mq[d][lane];
        }
        float inv = 1.f / dv;
        mo *= inv; qmo *= inv;
        float gqv = qmo * gwv[lane];
        for (int off = 32; off; off >>= 1) gqv += __shfl_xor(gqv, off, 64);
        float gq = sigmoidf(gqv + gbv);
        memcomb[(((size_t)bh)*S_ + s)*64 + lane] = __float2bfloat16(mo + gq * qmo);
        __syncthreads();
    }
}

// ---------------------------------------------------------------------------
// in-place RoPE on bf16 workspace (B,S,DIM)
// ---------------------------------------------------------------------------
__global__ void rope_kernel(bf16* __restrict__ buf, const void* __restrict__ fcos,
                            const void* __restrict__ fsin,
                            const int* __restrict__ flagp) {
    int f = *flagp;
    int pid = blockIdx.x * 256 + threadIdx.x;
    int cp = pid & 1023;
    int m  = pid >> 10;
    int s  = m & (S_-1);
    int p  = cp & 31;
    float c  = dread(fcos, s*32 + p, f);
    float sn = dread(fsin, s*32 + p, f);
    size_t idx = (size_t)m * DIM_ + cp*2;
    float a = b2f(buf[idx]), b = b2f(buf[idx+1]);
    buf[idx]   = __float2bfloat16(a*c - b*sn);
    buf[idx+1] = __float2bfloat16(a*sn + b*c);
}

// ---------------------------------------------------------------------------
// flash-style causal attention + gate-combine epilogue
// ---------------------------------------------------------------------------
__global__ __launch_bounds__(512)
void attn_kernel(const bf16* __restrict__ qr, const bf16* __restrict__ kr,
                 const bf16* __restrict__ v, const bf16* __restrict__ memcomb,
                 const void* __restrict__ gate, const int* __restrict__ flagp,
                 bf16* __restrict__ outc) {
    int f = *flagp;
    __shared__ float Ks[64][65];
    __shared__ float Vs[64][65];
    __shared__ float qs[16][64];
    __shared__ float ps[16][64];
    int bid = blockIdx.x;
    int qt = bid & 63;
    int h = (bid >> 6) & 31;
    int b = bid >> 11;
    int q0 = qt << 4;
    int t = threadIdx.x;
    int w = t >> 6, lane = t & 63;

    for (int i = t; i < 1024; i += 512) {
        int row = i >> 6, d = i & 63;
        qs[row][d] = b2f(qr[((size_t)(b*S_ + q0 + row))*DIM_ + h*64 + d]);
    }
    float m0 = -1e30f, m1 = -1e30f, l0 = 0.f, l1 = 0.f, O0 = 0.f, O1 = 0.f;
    int r0 = q0 + 2*w, r1 = r0 + 1;
    int nch = ((q0 + 15) >> 6) + 1;
    __syncthreads();

    for (int ch = 0; ch < nch; ++ch) {
        int j0 = ch << 6;
        for (int i = t; i < 4096; i += 512) {
            int row = i >> 6, d = i & 63;
            size_t src = ((size_t)(b*S_ + j0 + row))*DIM_ + h*64 + d;
            Ks[row][d] = b2f(kr[src]);
            Vs[row][d] = b2f(v[src]);
        }
        __syncthreads();
        float a0, a1;
        {
            int rl = 2*w;
            float sc = 0.f;
            #pragma unroll
            for (int d = 0; d < 64; ++d) sc += qs[rl][d] * Ks[lane][d];
            sc *= 0.125f;
            if (j0 + lane > r0) sc = -1e30f;
            float mx = sc;
            for (int off = 32; off; off >>= 1) mx = fmaxf(mx, __shfl_xor(mx, off, 64));
            float mn = fmaxf(m0, mx);
            a0 = __expf(m0 - mn);
            float p = __expf(sc - mn);
            float pS = p;
            for (int off = 32; off; off >>= 1) pS += __shfl_xor(pS, off, 64);
            l0 = l0 * a0 + pS;
            m0 = mn;
            ps[rl][lane] = p;
        }
        {
            int rl = 2*w + 1;
            float sc = 0.f;
            #pragma unroll
            for (int d = 0; d < 64; ++d) sc += qs[rl][d] * Ks[lane][d];
            sc *= 0.125f;
            if (j0 + lane > r1) sc = -1e30f;
            float mx = sc;
            for (int off = 32; off; off >>= 1) mx = fmaxf(mx, __shfl_xor(mx, off, 64));
            float mn = fmaxf(m1, mx);
            a1 = __expf(m1 - mn);
            float p = __expf(sc - mn);
            float pS = p;
            for (int off = 32; off; off >>= 1) pS += __shfl_xor(pS, off, 64);
            l1 = l1 * a1 + pS;
            m1 = mn;
            ps[rl][lane] = p;
        }
        __syncthreads();
        {
            float acc = 0.f;
            #pragma unroll
            for (int jj = 0; jj < 64; ++jj) acc += ps[2*w][jj] * Vs[jj][lane];
            O0 = O0 * a0 + acc;
        }
        {
            float acc = 0.f;
            #pragma unroll
            for (int jj = 0; jj < 64; ++jj) acc += ps[2*w+1][jj] * Vs[jj][lane];
            O1 = O1 * a1 + acc;
        }
        __syncthreads();
    }

    float g = sigmoidf(dread(gate, h, f));
    {
        float attn = O0 / l0;
        float comb = b2f(memcomb[(((size_t)(b*H_ + h))*S_ + r0)*64 + lane]);
        outc[((size_t)(b*S_ + r0))*DIM_ + h*64 + lane] =
            __float2bfloat16(g*comb + (1.f - g)*attn);
    }
    {
        float attn = O1 / l1;
        float comb = b2f(memcomb[(((size_t)(b*H_ + h))*S_ + r1)*64 + lane]);
        outc[((size_t)(b*S_ + r1))*DIM_ + h*64 + lane] =
            __float2bfloat16(g*comb + (1.f - g)*attn);
    }
}

// ---------------------------------------------------------------------------
extern "C" void kernel_launch(void* const* d_in, const int* in_sizes, int n_in,
                              void* d_out, int out_size, void* d_ws, size_t ws_size,
                              hipStream_t stream) {
    const void* x        = d_in[0];
    const void* pq       = d_in[1];
    const void* cache_k  = d_in[2];
    const void* cache_v  = d_in[3];
    const void* mem_long = d_in[4];
    const void* mem_qry  = d_in[5];
    const void* norm_t   = d_in[6];
    const void* fcos     = d_in[7];
    const void* fsin     = d_in[8];
    // d_in[9] = mask (unused; causal applied analytically)
    const void* wq  = d_in[10];
    const void* wk  = d_in[11];
    const void* wv  = d_in[12];
    const void* wo  = d_in[13];
    const void* lq1 = d_in[14];
    const void* lq2 = d_in[15];
    const void* lk1 = d_in[16];
    const void* lk2 = d_in[17];
    const void* lv1 = d_in[18];
    const void* lv2 = d_in[19];
    const void* lo1 = d_in[20];
    const void* lo2 = d_in[21];
    const void* gate = d_in[22];
    const void* gmw  = d_in[23];
    const void* gmb  = d_in[24];

    const size_t NBSD = (size_t)BS_ * DIM_;   // 8388608
    const size_t NW   = (size_t)DIM_ * DIM_;  // 4194304
    int*  flag = (int*)d_ws;
    bf16* xb   = (bf16*)((char*)d_ws + 16);   // converted x
    bf16* wbuf = xb + NBSD;                   // fused (W + L2*L1) bf16
    bf16* xq   = wbuf + NW;
    bf16* xk   = xq + NBSD;
    bf16* xv   = xk + NBSD;
    bf16* outc = xv + NBSD;
    float* qsig = (float*)(outc + NBSD);
    float* meml = qsig + (size_t)B_*H_*S_;
    float* memq = meml + (size_t)B_*H_*HD_*HD_;
    float* nrmt = memq + (size_t)B_*H_*HD_*HD_;
    bf16* memcomb = (bf16*)d_out;   // parked; final GEMM overwrites d_out

    dim3 ggrid(DIM_/128, BS_/128);  // (16, 32)
    dim3 wgrid(DIM_/256, DIM_);     // (8, 2048)

    // 0. dtype detect
    detect_kernel<<<1, 256, 0, stream>>>(x, flag);
    // 1. convert x to bf16
    convert_kernel<<<(int)(NBSD/256), 256, 0, stream>>>(x, xb, (int)NBSD, flag);
    // 2. projections: fold low-rank into weight, then MFMA GEMM
    wprep_kernel<<<wgrid, 256, 0, stream>>>(wq, lq1, lq2, flag, wbuf);
    gemm_mfma_kernel<1><<<ggrid, 256, 0, stream>>>(xb, wbuf, flag, xq);
    wprep_kernel<<<wgrid, 256, 0, stream>>>(wk, lk1, lk2, flag, wbuf);
    gemm_mfma_kernel<1><<<ggrid, 256, 0, stream>>>(xb, wbuf, flag, xk);
    wprep_kernel<<<wgrid, 256, 0, stream>>>(wv, lv1, lv2, flag, wbuf);
    gemm_mfma_kernel<1><<<ggrid, 256, 0, stream>>>(xb, wbuf, flag, xv);
    // 3. prompt-query scores
    qscore_kernel<<<(B_*H_*S_)/4, 256, 0, stream>>>(pq, cache_k, flag, qsig);
    // 4. memory accumulation
    mem_kernel<<<B_*H_, 256, 0, stream>>>(cache_k, cache_v, qsig, mem_long, mem_qry,
                                          norm_t, flag, meml, memq, nrmt);
    // 5. memory readout + gate (consumes UN-roped xq)
    memout_kernel<<<B_*H_, 256, 0, stream>>>(xq, meml, memq, nrmt, gmw, gmb, flag, memcomb);
    // 6. RoPE in place
    rope_kernel<<<(BS_*1024)/256, 256, 0, stream>>>(xq, fcos, fsin, flag);
    rope_kernel<<<(BS_*1024)/256, 256, 0, stream>>>(xk, fcos, fsin, flag);
    // 7. causal attention + combine epilogue
    attn_kernel<<<B_*H_*(S_/16), 512, 0, stream>>>(xq, xk, xv, memcomb, gate, flag, outc);
    // 8. output projection
    wprep_kernel<<<wgrid, 256, 0, stream>>>(wo, lo1, lo2, flag, wbuf);
    gemm_mfma_kernel<0><<<ggrid, 256, 0, stream>>>(outc, wbuf, flag, d_out);
}

// Round 5
// 1402.536 us; speedup vs baseline: 8.3836x; 1.8298x over previous
//
#include <hip/hip_runtime.h>
#include <hip/hip_bf16.h>

typedef __hip_bfloat16 bf16;
typedef __attribute__((ext_vector_type(8))) short short8;
typedef __attribute__((ext_vector_type(4))) float floatx4;

#define B_ 4
#define S_ 1024
#define DIM_ 2048
#define H_ 32
#define HD_ 64
#define R_ 16
#define BS_ (B_*S_)   // 4096

typedef __attribute__((address_space(1))) void GVoid;
typedef __attribute__((address_space(3))) void LVoid;
#define GLDS16(gp, lp) __builtin_amdgcn_global_load_lds((GVoid*)(gp), (LVoid*)(lp), 16, 0, 0)

__device__ __forceinline__ float b2f(bf16 v){ return __bfloat162float(v); }
__device__ __forceinline__ float elu1f(float x){ return x > 0.f ? x + 1.f : __expf(x); }
__device__ __forceinline__ float sigmoidf(float x){ return 1.f/(1.f + __expf(-x)); }
__device__ __forceinline__ float loadf(bf16 v){ return __bfloat162float(v); }
__device__ __forceinline__ float loadf(float v){ return v; }

// dtype-adaptive input read: f=1 -> bf16, f=0 -> fp32 (uniform branch).
__device__ __forceinline__ float dread(const void* p, size_t i, int f){
    float r;
    if (f) r = __bfloat162float(((const bf16*)p)[i]);
    else   r = ((const float*)p)[i];
    return r;
}
__device__ __forceinline__ void dwrite(void* p, size_t i, float v, int f){
    if (f) ((bf16*)p)[i] = __float2bfloat16(v);
    else   ((float*)p)[i] = v;
}

// ---------------------------------------------------------------------------
// dtype detect (same every call; graph-safe)
// ---------------------------------------------------------------------------
__global__ void detect_kernel(const void* __restrict__ x, int* __restrict__ flag){
    __shared__ int cnt[256];
    int t = threadIdx.x;
    int c = 0;
    for (int i = t; i < 4096; i += 256){
        float v = __bfloat162float(((const bf16*)x)[i]);
        float a = fabsf(v);
        if (a > 1e-3f && a < 1e3f) c++;
    }
    cnt[t] = c;
    __syncthreads();
    if (t == 0){
        int s = 0;
        for (int i = 0; i < 256; ++i) s += cnt[i];
        *flag = (s > 3686) ? 1 : 0;
    }
}

// ---------------------------------------------------------------------------
// convert input (fp32 or bf16 per flag) -> bf16 workspace copy
// ---------------------------------------------------------------------------
template<typename T>
__device__ __forceinline__ void convert_body(const T* __restrict__ src,
                                             bf16* __restrict__ dst, int n){
    int i = blockIdx.x * 256 + threadIdx.x;
    if (i < n) dst[i] = __float2bfloat16(loadf(src[i]));
}
__global__ void convert_kernel(const void* __restrict__ src, bf16* __restrict__ dst,
                               int n, const int* __restrict__ flagp){
    if (*flagp) convert_body((const bf16*)src, dst, n);
    else        convert_body((const float*)src, dst, n);
}

// ---------------------------------------------------------------------------
// fused weight prep: W'[n,k] = W[n,k] + sum_r L2[n,r] * L1[r,k]   -> bf16
// ---------------------------------------------------------------------------
template<typename T>
__device__ __forceinline__ void wprep_body(const T* __restrict__ W,
                                           const T* __restrict__ L1,
                                           const T* __restrict__ L2,
                                           bf16* __restrict__ dst){
    int n = blockIdx.y;
    int k = blockIdx.x * 256 + threadIdx.x;
    size_t nk = (size_t)n * DIM_ + k;
    float acc = loadf(W[nk]);
    #pragma unroll
    for (int r = 0; r < 16; ++r)
        acc += loadf(L2[n*16 + r]) * loadf(L1[(size_t)r*DIM_ + k]);
    dst[nk] = __float2bfloat16(acc);
}
__global__ __launch_bounds__(256)
void wprep_kernel(const void* __restrict__ W, const void* __restrict__ L1,
                  const void* __restrict__ L2, const int* __restrict__ flagp,
                  bf16* __restrict__ dst){
    if (*flagp) wprep_body((const bf16*)W, (const bf16*)L1, (const bf16*)L2, dst);
    else        wprep_body((const float*)W, (const float*)L1, (const float*)L2, dst);
}

// ---------------------------------------------------------------------------
// MFMA GEMM: C[m,n] = sum_k A[m,k]*Bw[n,k]  (m97 structure)
// ---------------------------------------------------------------------------
template<int CMODE>   // 1: bf16 ws out; 0: dual-dtype d_out
__global__ __launch_bounds__(256)
void gemm_mfma_kernel(const bf16* __restrict__ A, const bf16* __restrict__ Bw,
                      const int* __restrict__ flagp, void* __restrict__ C) {
    __shared__ bf16 Als[128*32];
    __shared__ bf16 Bls[128*32];
    int tid = threadIdx.x;
    int w = tid >> 6, lane = tid & 63;
    int wr = w >> 1, wc = w & 1;
    int rm0 = blockIdx.y * 128;
    int cn0 = blockIdx.x * 128;

    const bf16* gA = A  + (size_t)(rm0 + w*32 + (lane>>2)) * DIM_ + (lane&3)*8;
    const bf16* gB = Bw + (size_t)(cn0 + w*32 + (lane>>2)) * DIM_ + (lane&3)*8;
    bf16* lA0 = Als + (w*32)*32;
    bf16* lA1 = Als + (w*32+16)*32;
    bf16* lB0 = Bls + (w*32)*32;
    bf16* lB1 = Bls + (w*32+16)*32;

    floatx4 acc[4][4];
    #pragma unroll
    for (int i = 0; i < 4; ++i)
        #pragma unroll
        for (int j = 0; j < 4; ++j) acc[i][j] = (floatx4){0.f,0.f,0.f,0.f};

    int aoff[4], boff[4];
    #pragma unroll
    for (int i = 0; i < 4; ++i) {
        aoff[i] = (wr*64 + i*16 + (lane&15))*32 + (lane>>4)*8;
        boff[i] = (wc*64 + i*16 + (lane&15))*32 + (lane>>4)*8;
    }

    for (int kk = 0; kk < DIM_; kk += 32) {
        GLDS16(gA + kk,             lA0);
        GLDS16(gA + 16*DIM_ + kk,   lA1);
        GLDS16(gB + kk,             lB0);
        GLDS16(gB + 16*DIM_ + kk,   lB1);
        __syncthreads();
        short8 af[4], bf_[4];
        #pragma unroll
        for (int i = 0; i < 4; ++i) {
            af[i]  = *(const short8*)(Als + aoff[i]);
            bf_[i] = *(const short8*)(Bls + boff[i]);
        }
        #pragma unroll
        for (int i = 0; i < 4; ++i)
            #pragma unroll
            for (int j = 0; j < 4; ++j)
                acc[i][j] = __builtin_amdgcn_mfma_f32_16x16x32_bf16(
                    af[i], bf_[j], acc[i][j], 0, 0, 0);
        __syncthreads();
    }

    int f = (CMODE==0) ? *flagp : 1;
    #pragma unroll
    for (int i = 0; i < 4; ++i) {
        #pragma unroll
        for (int reg = 0; reg < 4; ++reg) {
            int m_loc = wr*64 + i*16 + (lane>>4)*4 + reg;
            #pragma unroll
            for (int j = 0; j < 4; ++j) {
                int n_loc = wc*64 + j*16 + (lane&15);
                float val = acc[i][j][reg];
                size_t idx = (size_t)(rm0 + m_loc) * DIM_ + cn0 + n_loc;
                if (CMODE==1) ((bf16*)C)[idx] = __float2bfloat16(val);
                else          dwrite(C, idx, val, f);
            }
        }
    }
}

// ---------------------------------------------------------------------------
// qsig[b,h,s] = sigmoid( dot(pq[b,h,:], cache_k[b,s,h,:]) / 8 )
// ---------------------------------------------------------------------------
__global__ void qscore_kernel(const void* __restrict__ pq, const void* __restrict__ ck,
                              const int* __restrict__ flagp, float* __restrict__ qsig) {
    int f = *flagp;
    int tid = threadIdx.x;
    int lane = tid & 63;
    int wid = (blockIdx.x << 2) | (tid >> 6);
    int s = wid & (S_-1);
    int h = (wid >> 10) & (H_-1);
    int b = wid >> 15;
    float p = dread(pq, ((size_t)b*H_ + h)*HD_ + lane, f);
    float k = dread(ck, (((size_t)b*S_ + s)*H_ + h)*HD_ + lane, f);
    float v = p * k;
    for (int off = 32; off; off >>= 1) v += __shfl_xor(v, off, 64);
    if (lane == 0) qsig[((size_t)b*H_ + h)*S_ + s] = sigmoidf(v * 0.125f);
}

// ---------------------------------------------------------------------------
// per (b,h): mem_l/mem_q outer-product accumulation + nrm
// ---------------------------------------------------------------------------
__global__ __launch_bounds__(256)
void mem_kernel(const void* __restrict__ ck, const void* __restrict__ cv,
                const float* __restrict__ qsig,
                const void* __restrict__ meml_in, const void* __restrict__ memq_in,
                const void* __restrict__ norm_in,
                const int* __restrict__ flagp,
                float* __restrict__ meml, float* __restrict__ memq,
                float* __restrict__ nrmt) {
    int f = *flagp;
    __shared__ float ks[4][64], vs[4][64], fv[4][64];
    int bh = blockIdx.x;
    int b = bh >> 5, h = bh & 31;
    int t = threadIdx.x;
    int e = t & 63;
    int dg = t >> 6;
    float accL[16] = {};
    float accQ[16] = {};
    float nsum = 0.f;
    for (int s0 = 0; s0 < S_; s0 += 4) {
        int sl = t >> 6, d = t & 63;
        int s = s0 + sl;
        size_t base = (((size_t)b*S_ + s)*H_ + h)*HD_ + d;
        float kv = elu1f(dread(ck, base, f));
        float vv = dread(cv, base, f);
        float sg = qsig[((size_t)b*H_ + h)*S_ + s];
        ks[sl][d] = kv;
        vs[sl][d] = vv;
        fv[sl][d] = vv * sg;
        __syncthreads();
        #pragma unroll
        for (int s2 = 0; s2 < 4; ++s2) {
            float ve = vs[s2][e];
            float fe = fv[s2][e];
            #pragma unroll
            for (int dd = 0; dd < 16; ++dd) {
                float kk = ks[s2][dg*16 + dd];
                accL[dd] += kk * ve;
                accQ[dd] += kk * fe;
            }
        }
        if (t < 64) {
            #pragma unroll
            for (int s2 = 0; s2 < 4; ++s2) nsum += ks[s2][t];
        }
        __syncthreads();
    }
    size_t mb = (size_t)bh * HD_ * HD_;
    #pragma unroll
    for (int dd = 0; dd < 16; ++dd) {
        int d = dg*16 + dd;
        meml[mb + d*64 + e] = dread(meml_in, mb + d*64 + e, f) + accL[dd];
        memq[mb + d*64 + e] = dread(memq_in, mb + d*64 + e, f) + accQ[dd];
    }
    if (t < 64) nrmt[(size_t)bh*64 + t] = dread(norm_in, (size_t)bh*64 + t, f) + nsum;
}

// ---------------------------------------------------------------------------
// memory readout + per-row gate -> memcomb (bf16, parked in d_out)
// ---------------------------------------------------------------------------
__global__ __launch_bounds__(256)
void memout_kernel(const bf16* __restrict__ xq, const float* __restrict__ meml,
                   const float* __restrict__ memq, const float* __restrict__ nrmt,
                   const void* __restrict__ gw, const void* __restrict__ gb,
                   const int* __restrict__ flagp, bf16* __restrict__ memcomb) {
    int f = *flagp;
    __shared__ float Ml[64][64];
    __shared__ float Mq[64][64];
    __shared__ float nr[64];
    __shared__ float gwv[64];
    __shared__ float sq[4][64];
    int bh = blockIdx.x;
    int b = bh >> 5, h = bh & 31;
    int t = threadIdx.x;
    int w = t >> 6, lane = t & 63;
    size_t mb = (size_t)bh * 4096;
    for (int i = t; i < 4096; i += 256) {
        Ml[i>>6][i&63] = meml[mb + i];
        Mq[i>>6][i&63] = memq[mb + i];
    }
    if (t < 64) { nr[t] = nrmt[(size_t)bh*64 + t]; gwv[t] = dread(gw, t, f); }
    float gbv = dread(gb, 0, f);
    __syncthreads();
    for (int s0 = 0; s0 < S_; s0 += 4) {
        int s = s0 + w;
        float x = b2f(xq[((size_t)(b*S_ + s))*DIM_ + h*64 + lane]);
        float sqv = elu1f(x);
        sq[w][lane] = sqv;
        float dv = sqv * nr[lane];
        for (int off = 32; off; off >>= 1) dv += __shfl_xor(dv, off, 64);
        __syncthreads();
        float mo = 0.f, qmo = 0.f;
        #pragma unroll
        for (int d = 0; d < 64; ++d) {
            float sqd = sq[w][d];
            mo  += sqd * Ml[d][lane];
            qmo += sqd * Mq[d][lane];
        }
        float inv = 1.f / dv;
        mo *= inv; qmo *= inv;
        float gqv = qmo * gwv[lane];
        for (int off = 32; off; off >>= 1) gqv += __shfl_xor(gqv, off, 64);
        float gq = sigmoidf(gqv + gbv);
        memcomb[(((size_t)bh)*S_ + s)*64 + lane] = __float2bfloat16(mo + gq * qmo);
        __syncthreads();
    }
}

// ---------------------------------------------------------------------------
// in-place RoPE on bf16 workspace (B,S,DIM)
// ---------------------------------------------------------------------------
__global__ void rope_kernel(bf16* __restrict__ buf, const void* __restrict__ fcos,
                            const void* __restrict__ fsin,
                            const int* __restrict__ flagp) {
    int f = *flagp;
    int pid = blockIdx.x * 256 + threadIdx.x;
    int cp = pid & 1023;
    int m  = pid >> 10;
    int s  = m & (S_-1);
    int p  = cp & 31;
    float c  = dread(fcos, s*32 + p, f);
    float sn = dread(fsin, s*32 + p, f);
    size_t idx = (size_t)m * DIM_ + cp*2;
    float a = b2f(buf[idx]), b = b2f(buf[idx+1]);
    buf[idx]   = __float2bfloat16(a*c - b*sn);
    buf[idx+1] = __float2bfloat16(a*sn + b*c);
}

// ---------------------------------------------------------------------------
// V transpose: vtg[(b*H+h)*64 + d][s] = xv[(b*S+s)][h*64+d]
// 64x64 tiles via LDS with xor-swizzled columns to dodge bank conflicts.
// ---------------------------------------------------------------------------
__global__ __launch_bounds__(256)
void vtrans_kernel(const bf16* __restrict__ xv, bf16* __restrict__ vtg) {
    __shared__ bf16 tile[64*72];
    int bh = blockIdx.x;
    int b = bh >> 5;
    int s0 = blockIdx.y * 64;
    int tid = threadIdx.x;
    // load 64 s-rows x 64 d, swizzle column-blocks by row
    for (int it = tid; it < 512; it += 256) {
        int row = it >> 3, blk = it & 7;
        short8 val = *(const short8*)(xv + (size_t)(b*S_ + s0 + row)*DIM_
                                      + (bh & 31)*64 + blk*8);
        *(short8*)(tile + row*72 + ((blk ^ (row & 7))*8)) = val;
    }
    __syncthreads();
    // write d-rows: thread (d = it>>3, s-block = it&7) gathers 8 s for fixed d
    for (int it = tid; it < 512; it += 256) {
        int d = it >> 3, sb = (it & 7)*8;
        short8 o;
        #pragma unroll
        for (int i = 0; i < 8; ++i) {
            int s = sb + i;
            o[i] = *(const short*)(tile + s*72 + (((d>>3) ^ (s & 7))*8) + (d & 7));
        }
        *(short8*)(vtg + ((size_t)bh*64 + d)*S_ + s0 + sb) = o;
    }
}

// ---------------------------------------------------------------------------
// MFMA flash attention + gate-combine epilogue.
// Block: (b,h,64-row Q-tile); 4 waves x 16 Q-rows. K-tiles of 64.
// QK^T and PV via mfma_f32_16x16x32_bf16; P transits LDS to A-layout.
// ---------------------------------------------------------------------------
__global__ __launch_bounds__(256)
void attn_mfma_kernel(const bf16* __restrict__ qr, const bf16* __restrict__ kr,
                      const bf16* __restrict__ vtg, const bf16* __restrict__ memcomb,
                      const void* __restrict__ gate, const int* __restrict__ flagp,
                      bf16* __restrict__ outc) {
    __shared__ bf16 Qs[64*72];
    __shared__ bf16 Ks[64*72];
    __shared__ bf16 Vt[64*72];   // [d][kk]
    __shared__ bf16 Ps[4][16*72];
    int bid = blockIdx.x;
    int qt = bid & 15;
    int h  = (bid >> 4) & 31;
    int b  = bid >> 9;
    int q0 = qt * 64;
    int tid = threadIdx.x;
    int w = tid >> 6, lane = tid & 63;
    int quad = lane >> 4, r16 = lane & 15;

    // stage Q tile
    for (int it = tid; it < 512; it += 256) {
        int row = it >> 3, c8 = (it & 7)*8;
        *(short8*)(Qs + row*72 + c8) =
            *(const short8*)(qr + (size_t)(b*S_ + q0 + row)*DIM_ + h*64 + c8);
    }
    __syncthreads();
    short8 qf[2];
    #pragma unroll
    for (int kb = 0; kb < 2; ++kb)
        qf[kb] = *(const short8*)(Qs + (w*16 + r16)*72 + kb*32 + quad*8);

    float mrow[4] = {-1e30f,-1e30f,-1e30f,-1e30f};
    float lrow[4] = {0.f,0.f,0.f,0.f};
    floatx4 Ox[4];
    #pragma unroll
    for (int db = 0; db < 4; ++db) Ox[db] = (floatx4){0.f,0.f,0.f,0.f};

    int ntiles = qt + 1;
    for (int kt = 0; kt < ntiles; ++kt) {
        int k0 = kt * 64;
        // stage K tile (rows [kk][d]) and Vt tile (rows [d][kk])
        for (int it = tid; it < 512; it += 256) {
            int row = it >> 3, c8 = (it & 7)*8;
            *(short8*)(Ks + row*72 + c8) =
                *(const short8*)(kr + (size_t)(b*S_ + k0 + row)*DIM_ + h*64 + c8);
            *(short8*)(Vt + row*72 + c8) =
                *(const short8*)(vtg + ((size_t)(b*H_ + h)*64 + row)*S_ + k0 + c8);
        }
        __syncthreads();

        // S strip: 16 q-rows x 64 k-cols per wave
        floatx4 Sbv[4];
        #pragma unroll
        for (int nb = 0; nb < 4; ++nb) {
            floatx4 a = (floatx4){0.f,0.f,0.f,0.f};
            #pragma unroll
            for (int kb = 0; kb < 2; ++kb) {
                short8 kf = *(const short8*)(Ks + (nb*16 + r16)*72 + kb*32 + quad*8);
                a = __builtin_amdgcn_mfma_f32_16x16x32_bf16(qf[kb], kf, a, 0, 0, 0);
            }
            Sbv[nb] = a;
        }
        // scale + causal mask
        float S4[4][4];
        #pragma unroll
        for (int nb = 0; nb < 4; ++nb)
            #pragma unroll
            for (int reg = 0; reg < 4; ++reg) {
                int qg = q0 + w*16 + quad*4 + reg;
                int kg = k0 + nb*16 + r16;
                float s = Sbv[nb][reg] * 0.125f;
                S4[nb][reg] = (kg > qg) ? -1e30f : s;
            }
        // online softmax (rows live across the 16 lanes of a quad)
        float alpha[4], rsum[4];
        #pragma unroll
        for (int reg = 0; reg < 4; ++reg) {
            float mx = fmaxf(fmaxf(S4[0][reg], S4[1][reg]),
                             fmaxf(S4[2][reg], S4[3][reg]));
            mx = fmaxf(mx, __shfl_xor(mx, 1, 64));
            mx = fmaxf(mx, __shfl_xor(mx, 2, 64));
            mx = fmaxf(mx, __shfl_xor(mx, 4, 64));
            mx = fmaxf(mx, __shfl_xor(mx, 8, 64));
            float mn = fmaxf(mrow[reg], mx);
            alpha[reg] = __expf(mrow[reg] - mn);
            mrow[reg] = mn;
            float rs = 0.f;
            #pragma unroll
            for (int nb = 0; nb < 4; ++nb) {
                float p = __expf(S4[nb][reg] - mn);
                S4[nb][reg] = p;
                rs += p;
            }
            rs += __shfl_xor(rs, 1, 64);
            rs += __shfl_xor(rs, 2, 64);
            rs += __shfl_xor(rs, 4, 64);
            rs += __shfl_xor(rs, 8, 64);
            rsum[reg] = rs;
            lrow[reg] = lrow[reg]*alpha[reg] + rs;
        }
        // P -> LDS (C-layout write), re-read as A-layout frags
        #pragma unroll
        for (int nb = 0; nb < 4; ++nb)
            #pragma unroll
            for (int reg = 0; reg < 4; ++reg)
                Ps[w][(quad*4 + reg)*72 + nb*16 + r16] = __float2bfloat16(S4[nb][reg]);
        short8 pf[2];
        #pragma unroll
        for (int kb = 0; kb < 2; ++kb)
            pf[kb] = *(const short8*)(&Ps[w][0] + r16*72 + kb*32 + quad*8);
        // O = O*alpha + P @ V
        #pragma unroll
        for (int db = 0; db < 4; ++db) {
            #pragma unroll
            for (int reg = 0; reg < 4; ++reg) Ox[db][reg] *= alpha[reg];
            #pragma unroll
            for (int kb = 0; kb < 2; ++kb) {
                short8 vf = *(const short8*)(Vt + (db*16 + r16)*72 + kb*32 + quad*8);
                Ox[db] = __builtin_amdgcn_mfma_f32_16x16x32_bf16(pf[kb], vf, Ox[db], 0, 0, 0);
            }
        }
        __syncthreads();   // protect K/Vt for next iteration's staging
    }

    int f = *flagp;
    float g = sigmoidf(dread(gate, h, f));
    #pragma unroll
    for (int db = 0; db < 4; ++db)
        #pragma unroll
        for (int reg = 0; reg < 4; ++reg) {
            int qg = q0 + w*16 + quad*4 + reg;
            int d  = db*16 + r16;
            float attn = Ox[db][reg] / lrow[reg];
            float comb = b2f(memcomb[((size_t)(b*H_ + h)*S_ + qg)*64 + d]);
            outc[(size_t)(b*S_ + qg)*DIM_ + h*64 + d] =
                __float2bfloat16(g*comb + (1.f - g)*attn);
        }
}

// ---------------------------------------------------------------------------
extern "C" void kernel_launch(void* const* d_in, const int* in_sizes, int n_in,
                              void* d_out, int out_size, void* d_ws, size_t ws_size,
                              hipStream_t stream) {
    const void* x        = d_in[0];
    const void* pq       = d_in[1];
    const void* cache_k  = d_in[2];
    const void* cache_v  = d_in[3];
    const void* mem_long = d_in[4];
    const void* mem_qry  = d_in[5];
    const void* norm_t   = d_in[6];
    const void* fcos     = d_in[7];
    const void* fsin     = d_in[8];
    // d_in[9] = mask (unused; causal applied analytically)
    const void* wq  = d_in[10];
    const void* wk  = d_in[11];
    const void* wv  = d_in[12];
    const void* wo  = d_in[13];
    const void* lq1 = d_in[14];
    const void* lq2 = d_in[15];
    const void* lk1 = d_in[16];
    const void* lk2 = d_in[17];
    const void* lv1 = d_in[18];
    const void* lv2 = d_in[19];
    const void* lo1 = d_in[20];
    const void* lo2 = d_in[21];
    const void* gate = d_in[22];
    const void* gmw  = d_in[23];
    const void* gmb  = d_in[24];

    const size_t NBSD = (size_t)BS_ * DIM_;   // 8388608
    const size_t NW   = (size_t)DIM_ * DIM_;  // 4194304
    int*  flag = (int*)d_ws;
    bf16* xb   = (bf16*)((char*)d_ws + 16);   // converted x
    bf16* wbuf = xb + NBSD;                   // fused (W + L2*L1) bf16
    bf16* xq   = wbuf + NW;
    bf16* xk   = xq + NBSD;
    bf16* xv   = xk + NBSD;
    bf16* outc = xv + NBSD;
    bf16* vtg  = outc + NBSD;                 // V transposed: [b,h,d,s]
    float* qsig = (float*)(vtg + NBSD);
    float* meml = qsig + (size_t)B_*H_*S_;
    float* memq = meml + (size_t)B_*H_*HD_*HD_;
    float* nrmt = memq + (size_t)B_*H_*HD_*HD_;
    bf16* memcomb = (bf16*)d_out;   // parked; final GEMM overwrites d_out

    dim3 ggrid(DIM_/128, BS_/128);  // (16, 32)
    dim3 wgrid(DIM_/256, DIM_);     // (8, 2048)

    // 0. dtype detect
    detect_kernel<<<1, 256, 0, stream>>>(x, flag);
    // 1. convert x to bf16
    convert_kernel<<<(int)(NBSD/256), 256, 0, stream>>>(x, xb, (int)NBSD, flag);
    // 2. projections: fold low-rank into weight, then MFMA GEMM
    wprep_kernel<<<wgrid, 256, 0, stream>>>(wq, lq1, lq2, flag, wbuf);
    gemm_mfma_kernel<1><<<ggrid, 256, 0, stream>>>(xb, wbuf, flag, xq);
    wprep_kernel<<<wgrid, 256, 0, stream>>>(wk, lk1, lk2, flag, wbuf);
    gemm_mfma_kernel<1><<<ggrid, 256, 0, stream>>>(xb, wbuf, flag, xk);
    wprep_kernel<<<wgrid, 256, 0, stream>>>(wv, lv1, lv2, flag, wbuf);
    gemm_mfma_kernel<1><<<ggrid, 256, 0, stream>>>(xb, wbuf, flag, xv);
    // 3. V transpose for MFMA attention
    vtrans_kernel<<<dim3(B_*H_, S_/64), 256, 0, stream>>>(xv, vtg);
    // 4. prompt-query scores
    qscore_kernel<<<(B_*H_*S_)/4, 256, 0, stream>>>(pq, cache_k, flag, qsig);
    // 5. memory accumulation
    mem_kernel<<<B_*H_, 256, 0, stream>>>(cache_k, cache_v, qsig, mem_long, mem_qry,
                                          norm_t, flag, meml, memq, nrmt);
    // 6. memory readout + gate (consumes UN-roped xq)
    memout_kernel<<<B_*H_, 256, 0, stream>>>(xq, meml, memq, nrmt, gmw, gmb, flag, memcomb);
    // 7. RoPE in place
    rope_kernel<<<(BS_*1024)/256, 256, 0, stream>>>(xq, fcos, fsin, flag);
    rope_kernel<<<(BS_*1024)/256, 256, 0, stream>>>(xk, fcos, fsin, flag);
    // 8. MFMA causal attention + combine epilogue
    attn_mfma_kernel<<<B_*H_*(S_/64), 256, 0, stream>>>(xq, xk, vtg, memcomb,
                                                        gate, flag, outc);
    // 9. output projection
    wprep_kernel<<<wgrid, 256, 0, stream>>>(wo, lo1, lo2, flag, wbuf);
    gemm_mfma_kernel<0><<<ggrid, 256, 0, stream>>>(outc, wbuf, flag, d_out);
}